// Round 1
// baseline (74.969 us; speedup 1.0000x reference)
//
#include <hip/hip_runtime.h>

// Problem constants (from reference):
// x:      (B=2, C=64, D=16, H=64, W=64) fp32
// weight: (B=2, heads=1, wc=16, kvol=27, Do=16, Ho=64, Wo=64) fp32
// out:    (B=2, 64, 16, 64, 64) fp32
// out[b, q*16+c, do,ho,wo] = sum_{kd,kh,kw} x[b, q*16+c, do+kd-1, ho+kh-1, wo+kw-1]
//                                           * weight[b, 0, c, (kd*3+kh)*3+kw, do,ho,wo]

#define D_DIM 16
#define H_DIM 64
#define W_DIM 64
#define NQ 4

__global__ __launch_bounds__(256) void lconv_kernel(
    const float* __restrict__ x, const float* __restrict__ wt, float* __restrict__ out)
{
    const int tid = threadIdx.x;
    const int tw  = tid & 15;   // which group of 4 wo
    const int th  = tid >> 4;   // ho within 16-row tile

    int bid = blockIdx.x;
    const int ho_tile = bid & 3;  bid >>= 2;
    const int dout    = bid & 15; bid >>= 4;
    const int c       = bid & 15; bid >>= 4;
    const int b       = bid;      // 0..1

    const int ho  = ho_tile * 16 + th;
    const int wo0 = tw * 4;

    float acc[NQ][4];
    #pragma unroll
    for (int q = 0; q < NQ; ++q)
        #pragma unroll
        for (int j = 0; j < 4; ++j) acc[q][j] = 0.f;

    // weight base at k=0: (((b*16 + c)*27 + k)*16 + dout)*4096 + ho*64 + wo0
    const float* wbase = wt + (((size_t)(b * 16 + c) * 27) * 16 + dout) * 4096
                            + ho * 64 + wo0;

    #pragma unroll
    for (int dd = 0; dd < 3; ++dd) {
        const int d = dout + dd - 1;
        if (d < 0 || d >= D_DIM) continue;          // uniform per block
        #pragma unroll
        for (int dh = 0; dh < 3; ++dh) {
            const int h = ho + dh - 1;
            if (h < 0 || h >= H_DIM) continue;      // diverges only in edge waves

            // Load x window [wo0-1, wo0+4] for all 4 q-groups.
            float xv[NQ][6];
            #pragma unroll
            for (int q = 0; q < NQ; ++q) {
                const float* xrow = x + ((size_t)(b * 64 + q * 16 + c) * 16 + d) * 4096
                                      + h * 64 + wo0;
                const float4 v = *reinterpret_cast<const float4*>(xrow);
                xv[q][1] = v.x; xv[q][2] = v.y; xv[q][3] = v.z; xv[q][4] = v.w;
                xv[q][0] = (tw > 0)  ? xrow[-1] : 0.f;   // W-pad
                xv[q][5] = (tw < 15) ? xrow[4]  : 0.f;   // W-pad
            }

            #pragma unroll
            for (int dw = 0; dw < 3; ++dw) {
                const int k = (dd * 3 + dh) * 3 + dw;
                const float4 w4 = *reinterpret_cast<const float4*>(wbase + (size_t)k * 65536);
                #pragma unroll
                for (int q = 0; q < NQ; ++q) {
                    acc[q][0] = fmaf(xv[q][0 + dw], w4.x, acc[q][0]);
                    acc[q][1] = fmaf(xv[q][1 + dw], w4.y, acc[q][1]);
                    acc[q][2] = fmaf(xv[q][2 + dw], w4.z, acc[q][2]);
                    acc[q][3] = fmaf(xv[q][3 + dw], w4.w, acc[q][3]);
                }
            }
        }
    }

    #pragma unroll
    for (int q = 0; q < NQ; ++q) {
        float* orow = out + ((size_t)(b * 64 + q * 16 + c) * 16 + dout) * 4096
                          + ho * 64 + wo0;
        *reinterpret_cast<float4*>(orow) =
            make_float4(acc[q][0], acc[q][1], acc[q][2], acc[q][3]);
    }
}

extern "C" void kernel_launch(void* const* d_in, const int* in_sizes, int n_in,
                              void* d_out, int out_size, void* d_ws, size_t ws_size,
                              hipStream_t stream) {
    const float* x  = (const float*)d_in[0];
    const float* wt = (const float*)d_in[1];
    float* out      = (float*)d_out;

    // 2048 blocks: (b=2) x (c=16) x (do=16) x (ho_tile=4), ho_tile innermost
    dim3 grid(2048), block(256);
    hipLaunchKernelGGL(lconv_kernel, grid, block, 0, stream, x, wt, out);
}

// Round 2
// 62.122 us; speedup vs baseline: 1.2068x; 1.2068x over previous
//
#include <hip/hip_runtime.h>

// out[b, q*16+c, do,ho,wo] = sum_{kd,kh,kw} x[b, q*16+c, do+kd-1, ho+kh-1, wo+kw-1]
//                                           * weight[b, 0, c, (kd*3+kh)*3+kw, do,ho,wo]
// x: (2,64,16,64,64) f32; weight: (2,1,16,27,16,64,64) f32; out: (2,64,16,64,64) f32

#define D_DIM 16
#define H_DIM 64
#define NQ 4

typedef float f4_t __attribute__((ext_vector_type(4)));

__global__ __launch_bounds__(256) void lconv_kernel(
    const float* __restrict__ x, const float* __restrict__ wt, float* __restrict__ out)
{
    const int tid = threadIdx.x;
    const int tw  = tid & 15;   // which group of 4 wo
    const int th  = tid >> 4;   // ho within 16-row tile

    int bid = blockIdx.x;
    const int ho_tile = bid & 3;  bid >>= 2;
    const int dout    = bid & 15; bid >>= 4;
    const int c       = bid & 15; bid >>= 4;
    const int b       = bid;      // 0..1

    const int ho  = ho_tile * 16 + th;
    const int wo0 = tw * 4;

    float acc[NQ][4];
    #pragma unroll
    for (int q = 0; q < NQ; ++q)
        #pragma unroll
        for (int j = 0; j < 4; ++j) acc[q][j] = 0.f;

    // weight base at k=0: (((b*16 + c)*27 + k)*16 + dout)*4096 + ho*64 + wo0
    const float* wbase = wt + (((size_t)(b * 16 + c) * 27) * 16 + dout) * 4096
                            + (size_t)ho * 64 + wo0;

    // per-q x base (plane stride 4096 floats)
    const float* xq[NQ];
    #pragma unroll
    for (int q = 0; q < NQ; ++q)
        xq[q] = x + ((size_t)(b * 64 + q * 16 + c) * 16) * 4096 + (size_t)wo0;

    #pragma unroll
    for (int dd = 0; dd < 3; ++dd) {
        const int d   = dout + dd - 1;
        const bool dok = (unsigned)d < (unsigned)D_DIM;   // block-uniform
        const int dc  = d < 0 ? 0 : (d > D_DIM - 1 ? D_DIM - 1 : d);
        #pragma unroll
        for (int dh = 0; dh < 3; ++dh) {
            const int h    = ho + dh - 1;
            const bool hok = (unsigned)h < (unsigned)H_DIM;
            const int hc   = h < 0 ? 0 : (h > H_DIM - 1 ? H_DIM - 1 : h);
            const bool ok  = dok && hok;
            const int xoff = dc * 4096 + hc * 64;

            // x window [wo0-1, wo0+5) for each q: one float4 + 2 shuffles
            float xv[NQ][6];
            #pragma unroll
            for (int q = 0; q < NQ; ++q) {
                f4_t v = *reinterpret_cast<const f4_t*>(xq[q] + xoff);
                v.x = ok ? v.x : 0.f;
                v.y = ok ? v.y : 0.f;
                v.z = ok ? v.z : 0.f;
                v.w = ok ? v.w : 0.f;
                const float xl = __shfl_up(v.w, 1);    // lane tw-1's last element
                const float xr = __shfl_down(v.x, 1);  // lane tw+1's first element
                xv[q][0] = (tw > 0)  ? xl : 0.f;       // W-pad left
                xv[q][1] = v.x; xv[q][2] = v.y; xv[q][3] = v.z; xv[q][4] = v.w;
                xv[q][5] = (tw < 15) ? xr : 0.f;       // W-pad right
            }

            #pragma unroll
            for (int dw = 0; dw < 3; ++dw) {
                const int k = (dd * 3 + dh) * 3 + dw;
                const f4_t w4 = __builtin_nontemporal_load(
                    reinterpret_cast<const f4_t*>(wbase + (size_t)k * 65536));
                #pragma unroll
                for (int q = 0; q < NQ; ++q) {
                    acc[q][0] = fmaf(xv[q][0 + dw], w4.x, acc[q][0]);
                    acc[q][1] = fmaf(xv[q][1 + dw], w4.y, acc[q][1]);
                    acc[q][2] = fmaf(xv[q][2 + dw], w4.z, acc[q][2]);
                    acc[q][3] = fmaf(xv[q][3 + dw], w4.w, acc[q][3]);
                }
            }
        }
    }

    #pragma unroll
    for (int q = 0; q < NQ; ++q) {
        float* orow = out + ((size_t)(b * 64 + q * 16 + c) * 16 + dout) * 4096
                          + (size_t)ho * 64 + wo0;
        f4_t r; r.x = acc[q][0]; r.y = acc[q][1]; r.z = acc[q][2]; r.w = acc[q][3];
        __builtin_nontemporal_store(r, reinterpret_cast<f4_t*>(orow));
    }
}

extern "C" void kernel_launch(void* const* d_in, const int* in_sizes, int n_in,
                              void* d_out, int out_size, void* d_ws, size_t ws_size,
                              hipStream_t stream) {
    const float* x  = (const float*)d_in[0];
    const float* wt = (const float*)d_in[1];
    float* out      = (float*)d_out;

    // 2048 blocks: (b=2) x (c=16) x (do=16) x (ho_tile=4), ho_tile innermost
    dim3 grid(2048), block(256);
    hipLaunchKernelGGL(lconv_kernel, grid, block, 0, stream, x, wt, out);
}

// Round 3
// 59.488 us; speedup vs baseline: 1.2602x; 1.0443x over previous
//
#include <hip/hip_runtime.h>

// out[b, q*16+c, do,ho,wo] = sum_{kd,kh,kw} x[b, q*16+c, do+kd-1, ho+kh-1, wo+kw-1]
//                                           * weight[b, 0, c, (kd*3+kh)*3+kw, do,ho,wo]
// x: (2,64,16,64,64) f32; weight: (2,1,16,27,16,64,64) f32; out: (2,64,16,64,64) f32

#define D_DIM 16
#define NQ 4
#define RS 68   // LDS row stride in floats (64 data + [64]=0 pad-R + [65]=0 pad-L + 2 spare)

typedef float f4_t __attribute__((ext_vector_type(4)));

__global__ __launch_bounds__(256) void lconv_kernel(
    const float* __restrict__ x, const float* __restrict__ wt, float* __restrict__ out)
{
    // lds[buf][q][h_local(18)][RS]
    __shared__ __align__(16) float lds[2][NQ][18][RS];

    const int tid = threadIdx.x;
    const int tw  = tid & 15;   // group of 4 wo
    const int th  = tid >> 4;   // ho within 16-row tile

    int bid = blockIdx.x;
    const int ho_tile = bid & 3;  bid >>= 2;
    const int dout    = bid & 15; bid >>= 4;
    const int c       = bid & 15; bid >>= 4;
    const int b       = bid;      // 0..1

    const int ho_base = ho_tile * 16;
    const int ho  = ho_base + th;
    const int wo0 = tw * 4;
    const int lw  = (tw == 0) ? 65 : (wo0 - 1);   // left-edge LDS index (65 = zero pad)

    // ---- one-time zero of pad columns ([64..67]) and the OOB halo row ----
    {
        float* l0 = &lds[0][0][0][0];
        for (int i = tid; i < 2 * NQ * 18 * 4; i += 256) {     // 576 words
            const int word = 64 + (i & 3);
            const int idx  = i >> 2;                            // bq*18 + h
            l0[(size_t)idx * RS + word] = 0.f;
        }
        const int oob_h = (ho_tile == 0) ? 0 : (ho_tile == 3) ? 17 : -1;
        if (oob_h >= 0) {
            for (int i = tid; i < 2 * NQ * RS; i += 256) {      // 544 words
                const int bq = i / RS, w = i - bq * RS;
                l0[((size_t)bq * 18 + oob_h) * RS + w] = 0.f;
            }
        }
    }

    // x base for this (b,c), q=0, d=0 ; q adds q*1048576, d adds d*4096
    const float* xbase = x + ((size_t)(b * 64 + c) * 16) * 4096;

    // stage plane d into lds[buf]  (rows with OOB gh skipped -> stay zero)
    auto stage = [&](int buf, int d) {
        const float* src = xbase + (size_t)d * 4096;
        for (int i = tid; i < 72 * 16; i += 256) {   // 72 rows x 16 float4-segs
            const int row = i >> 4;                  // 0..71
            const int seg = i & 15;
            const int q   = row / 18;
            const int hl  = row - q * 18;            // 0..17
            const int gh  = ho_base - 1 + hl;
            if ((unsigned)gh < 64u) {
                const f4_t v = *reinterpret_cast<const f4_t*>(
                    src + (size_t)q * 1048576 + (size_t)gh * 64 + seg * 4);
                *reinterpret_cast<f4_t*>(&lds[buf][q][hl][seg * 4]) = v;
            }
        }
    };

    float acc[NQ][4];
    #pragma unroll
    for (int q = 0; q < NQ; ++q)
        #pragma unroll
        for (int j = 0; j < 4; ++j) acc[q][j] = 0.f;

    // weight base at k=0
    const float* wbase = wt + (((size_t)(b * 16 + c) * 27) * 16 + dout) * 4096
                            + (size_t)ho * 64 + wo0;

    if (dout - 1 >= 0) stage(0, dout - 1);
    __syncthreads();

    #pragma unroll
    for (int dd = 0; dd < 3; ++dd) {
        const int cur = dd & 1, nxt = cur ^ 1;
        const int dn = dout + dd;                  // plane for iteration dd+1
        if (dd < 2 && dn < D_DIM) stage(nxt, dn);

        const int d = dout + dd - 1;
        if ((unsigned)d < (unsigned)D_DIM) {
            #pragma unroll
            for (int dh = 0; dh < 3; ++dh) {
                float xv[NQ][6];
                #pragma unroll
                for (int q = 0; q < NQ; ++q) {
                    const float* r = &lds[cur][q][th + dh][0];
                    const f4_t m = *reinterpret_cast<const f4_t*>(r + wo0);
                    xv[q][0] = r[lw];
                    xv[q][1] = m.x; xv[q][2] = m.y; xv[q][3] = m.z; xv[q][4] = m.w;
                    xv[q][5] = r[wo0 + 4];
                }
                #pragma unroll
                for (int dw = 0; dw < 3; ++dw) {
                    const int k = (dd * 3 + dh) * 3 + dw;
                    const f4_t w4 = __builtin_nontemporal_load(
                        reinterpret_cast<const f4_t*>(wbase + (size_t)k * 65536));
                    #pragma unroll
                    for (int q = 0; q < NQ; ++q) {
                        acc[q][0] = fmaf(xv[q][0 + dw], w4.x, acc[q][0]);
                        acc[q][1] = fmaf(xv[q][1 + dw], w4.y, acc[q][1]);
                        acc[q][2] = fmaf(xv[q][2 + dw], w4.z, acc[q][2]);
                        acc[q][3] = fmaf(xv[q][3 + dw], w4.w, acc[q][3]);
                    }
                }
            }
        }
        __syncthreads();
    }

    #pragma unroll
    for (int q = 0; q < NQ; ++q) {
        float* orow = out + ((size_t)(b * 64 + q * 16 + c) * 16 + dout) * 4096
                          + (size_t)ho * 64 + wo0;
        f4_t r; r.x = acc[q][0]; r.y = acc[q][1]; r.z = acc[q][2]; r.w = acc[q][3];
        __builtin_nontemporal_store(r, reinterpret_cast<f4_t*>(orow));
    }
}

extern "C" void kernel_launch(void* const* d_in, const int* in_sizes, int n_in,
                              void* d_out, int out_size, void* d_ws, size_t ws_size,
                              hipStream_t stream) {
    const float* x  = (const float*)d_in[0];
    const float* wt = (const float*)d_in[1];
    float* out      = (float*)d_out;

    // 2048 blocks: (b=2) x (c=16) x (do=16) x (ho_tile=4), ho_tile innermost
    dim3 grid(2048), block(256);
    hipLaunchKernelGGL(lconv_kernel, grid, block, 0, stream, x, wt, out);
}